// Round 8
// baseline (5972.269 us; speedup 1.0000x reference)
//
#include <hip/hip_runtime.h>
#include <hip/hip_fp16.h>

#define T_LEN 1024
#define B_SZ  32
#define D_IN  768
#define H_SZ  768
#define G4    3072   // 4*H
#define FPAD  32     // counter padding: 1 per 128-byte line
#define LDA   40     // xg_gemm: padded LDS row stride (bf16) for 32-wide K tiles
#define HPAD  776    // lstm_rec: padded row stride (bf16): uniform 8-way b128 = floor

typedef __attribute__((ext_vector_type(8))) short short8;   // 8 bf16 (4 VGPRs)
typedef __attribute__((ext_vector_type(4))) float f32x4;    // MFMA frag / 16B
typedef __attribute__((ext_vector_type(4))) unsigned u32x4; // asm-friendly 16B

// ---------------------------------------------------------------------------
// Packed-h exchange: producer-side bf16 hi/lo split. [domain c][parity][b][k]
// as u16. 384 KB total -> L3-resident. Written by combine threads with
// global_store_short sc0 sc1; read by stage with dwordx4 sc0 sc1. Parity
// reuse is safe by the transitive counter argument (cnt>=16(t+1) => every WG
// finished its step-t stage reads of the t-1 slot).
// ---------------------------------------------------------------------------
__device__ unsigned short xch_hi[2 * 2 * 16 * 768];
__device__ unsigned short xch_lo[2 * 2 * 16 * 768];

// bitwise fp32 -> bf16 hi/lo split (exact residual; 3-term MFMA error ~2^-16 rel)
__device__ __forceinline__ void split2(float x0, float x1, unsigned& hp, unsigned& lp)
{
    const unsigned u0 = __float_as_uint(x0);
    const unsigned u1 = __float_as_uint(x1);
    const unsigned h0 = u0 & 0xffff0000u, h1 = u1 & 0xffff0000u;
    hp = (h0 >> 16) | h1;
    const float l0 = x0 - __uint_as_float(h0);
    const float l1 = x1 - __uint_as_float(h1);
    lp = (__float_as_uint(l0) >> 16) | (__float_as_uint(l1) & 0xffff0000u);
}

// ---------------------------------------------------------------------------
// Phase A: split-bf16 3-term MFMA GEMM (verified R1/R2: ~0.36 ms). Epilogue
// writes xg in consumer-dense layout xg[t][c][r][gate][cb][cj] (verified R5:
// FETCH 664->370 MB). Unchanged.
// ---------------------------------------------------------------------------
__global__ __launch_bounds__(256, 2)
void xg_gemm(const float* __restrict__ hidden, const float* __restrict__ W_ih,
             const float* __restrict__ b_ih, const float* __restrict__ b_hh,
             __half* __restrict__ xg)
{
    __shared__ unsigned short Ah[128 * LDA];
    __shared__ unsigned short Al[128 * LDA];
    __shared__ unsigned short Bh[128 * LDA];
    __shared__ unsigned short Bl[128 * LDA];

    const int tid = threadIdx.x;
    const int n0 = blockIdx.x * 128;
    const int m0 = blockIdx.y * 128;

    const int srow = tid >> 1;
    const int skh  = (tid & 1) * 16;
    const int m = m0 + srow;
    const float* arow = hidden + ((size_t)(m & 31) * T_LEN + (m >> 5)) * D_IN;
    const float* brow = W_ih + (size_t)(n0 + srow) * D_IN;

    const int lane = tid & 63;
    const int wid  = tid >> 6;
    const int wm = (wid >> 1) * 64;
    const int wn = (wid & 1) * 64;
    const int fr = lane & 15;
    const int fk = (lane >> 4) * 8;

    f32x4 acc[4][4];
#pragma unroll
    for (int i = 0; i < 4; ++i)
#pragma unroll
        for (int j = 0; j < 4; ++j) acc[i][j] = (f32x4)0.f;

    float4 av[4], bv[4];
#pragma unroll
    for (int q = 0; q < 4; ++q) {
        av[q] = *(const float4*)(arow + skh + 4 * q);
        bv[q] = *(const float4*)(brow + skh + 4 * q);
    }

    for (int kb = 0; kb < D_IN; kb += 32) {
        __syncthreads();
        {
            const float* f = (const float*)av;
            unsigned hp[8], lp[8];
#pragma unroll
            for (int p = 0; p < 8; ++p) split2(f[2 * p], f[2 * p + 1], hp[p], lp[p]);
            *(uint4*)&Ah[srow * LDA + skh]     = make_uint4(hp[0], hp[1], hp[2], hp[3]);
            *(uint4*)&Ah[srow * LDA + skh + 8] = make_uint4(hp[4], hp[5], hp[6], hp[7]);
            *(uint4*)&Al[srow * LDA + skh]     = make_uint4(lp[0], lp[1], lp[2], lp[3]);
            *(uint4*)&Al[srow * LDA + skh + 8] = make_uint4(lp[4], lp[5], lp[6], lp[7]);
        }
        {
            const float* f = (const float*)bv;
            unsigned hp[8], lp[8];
#pragma unroll
            for (int p = 0; p < 8; ++p) split2(f[2 * p], f[2 * p + 1], hp[p], lp[p]);
            *(uint4*)&Bh[srow * LDA + skh]     = make_uint4(hp[0], hp[1], hp[2], hp[3]);
            *(uint4*)&Bh[srow * LDA + skh + 8] = make_uint4(hp[4], hp[5], hp[6], hp[7]);
            *(uint4*)&Bl[srow * LDA + skh]     = make_uint4(lp[0], lp[1], lp[2], lp[3]);
            *(uint4*)&Bl[srow * LDA + skh + 8] = make_uint4(lp[4], lp[5], lp[6], lp[7]);
        }
        __syncthreads();

        if (kb + 32 < D_IN) {
#pragma unroll
            for (int q = 0; q < 4; ++q) {
                av[q] = *(const float4*)(arow + kb + 32 + skh + 4 * q);
                bv[q] = *(const float4*)(brow + kb + 32 + skh + 4 * q);
            }
        }

        short8 afh[4], afl[4], bfh[4], bfl[4];
#pragma unroll
        for (int i = 0; i < 4; ++i) {
            afh[i] = *(const short8*)&Ah[(wm + i * 16 + fr) * LDA + fk];
            afl[i] = *(const short8*)&Al[(wm + i * 16 + fr) * LDA + fk];
            bfh[i] = *(const short8*)&Bh[(wn + i * 16 + fr) * LDA + fk];
            bfl[i] = *(const short8*)&Bl[(wn + i * 16 + fr) * LDA + fk];
        }
#pragma unroll
        for (int i = 0; i < 4; ++i)
#pragma unroll
            for (int j = 0; j < 4; ++j) {
                acc[i][j] = __builtin_amdgcn_mfma_f32_16x16x32_bf16(afh[i], bfh[j], acc[i][j], 0, 0, 0);
                acc[i][j] = __builtin_amdgcn_mfma_f32_16x16x32_bf16(afh[i], bfl[j], acc[i][j], 0, 0, 0);
                acc[i][j] = __builtin_amdgcn_mfma_f32_16x16x32_bf16(afl[i], bfh[j], acc[i][j], 0, 0, 0);
            }
    }

    const int rbase = (lane >> 4) * 4;
#pragma unroll
    for (int j = 0; j < 4; ++j) {
        const int gg = n0 + wn + j * 16 + fr;       // global gate-column
        const int gate = gg / 768;
        const int u    = gg - gate * 768;
        const int rq   = u / 6;
        const int cj   = u - rq * 6;
        const float bias = b_ih[gg] + b_hh[gg];
        const size_t cbase = (size_t)rq * 384 + gate * 96 + cj;
#pragma unroll
        for (int i = 0; i < 4; ++i) {
#pragma unroll
            for (int rx = 0; rx < 4; ++rx) {
                const int mm = m0 + wm + i * 16 + rbase + rx;
                const int t = mm >> 5, b = mm & 31;
                const size_t addr = (((size_t)t * 2 + (b >> 4)) * 128) * 384
                                    + cbase + (b & 15) * 6;
                xg[addr] = __float2half_rn(acc[i][j][rx] + bias);
            }
        }
    }
}

// ---------------------------------------------------------------------------
__global__ void zero_cnt(unsigned* flags) {
    flags[blockIdx.x * 1024 + threadIdx.x] = 0u;
}

// fast tanh via v_exp_f32; ~1e-7 abs error, no overflow (e<=1).
__device__ __forceinline__ float fast_tanh(float x) {
    const float e = __expf(-2.f * fabsf(x));
    const float r = __fdividef(1.f - e, 1.f + e);
    return copysignf(r, x);
}

// ---------------------------------------------------------------------------
// Phase B: persistent cooperative recurrence, 512 threads. R8: publish/poll
// via 8 MONOTONE AGGREGATE COUNTERS per domain (line-padded):
//  - producer r adds 1 to counter (r&7) each step (relaxed agent atomic;
//    16 producers/line, adds arrive spread in time -> negligible serialize)
//  - consumer at step t waits cnt[i] >= 16*t, i<8 -- EIGHT L3 line-requests
//    per WG per sweep instead of 128 (16x cut of the dominant L3 traffic)
//  - pollers live in wave 7 (tid 448..455): no outstanding vmem at poll time,
//    so the poll's vmcnt wait never serializes behind xg HBM prefetches
//  - monotone counters: no reset, no reuse hazard; max 16*1024 fits u32
// Everything else (xch exchange, MFMA dot, reduce, combine, drain): R7-exact.
// ---------------------------------------------------------------------------
__global__ void __launch_bounds__(512, 1)
lstm_rec(const __half* __restrict__ xg, const float* __restrict__ Whh,
         float* __restrict__ out, unsigned* __restrict__ flags)
{
    extern __shared__ char smc[];
    unsigned short* Wh_s = (unsigned short*)smc;                 // 24*776*2 = 37248
    unsigned short* Wl_s = (unsigned short*)(smc + 37248);       // 37248
    unsigned short* Hh_s = (unsigned short*)(smc + 74496);       // 16*776*2 = 24832
    unsigned short* Hl_s = (unsigned short*)(smc + 99328);       // 24832
    float*          rbuf = (float*)(smc + 124160);               // 8*512*4 = 16384
    float*          G    = (float*)(smc + 140544);               // 384*4 -> 142080

    const int tid = threadIdx.x;             // 0..511
    const int wg  = blockIdx.x;
    const int c   = wg & 1;        // batch group (sync domain)
    const int r   = wg >> 1;       // unit group 0..127
    const int u0  = r * 6;
    const int b0  = c * 16;

    // ---- load + split W_hh slice once: rows (gate*768 + u0 + j) ----
    for (int i = tid; i < 24 * 192; i += 512) {
        const int rr2 = i / 192;             // local row 0..23
        const int kc = (i % 192) * 4;
        const int gate = rr2 / 6, j = rr2 % 6;
        const float4 v = *(const float4*)&Whh[(size_t)(gate * H_SZ + u0 + j) * H_SZ + kc];
        unsigned h01, l01, h23, l23;
        split2(v.x, v.y, h01, l01);
        split2(v.z, v.w, h23, l23);
        *(uint2*)&Wh_s[rr2 * HPAD + kc] = make_uint2(h01, h23);
        *(uint2*)&Wl_s[rr2 * HPAD + kc] = make_uint2(l01, l23);
    }

    // MFMA roles (R2-verified layout)
    const int lane = tid & 63;
    const int wv   = tid >> 6;               // wave = K-eighth owner
    const int fr   = lane & 15;              // frag row (W) / batch row (h)
    const int fkb  = (lane >> 4) * 8;        // frag k offset
    const int rb4  = (lane >> 4) * 4;        // D frag row base
    // stage role: one batch row, 24 consecutive k per thread
    const int sb   = tid >> 5;               // batch 0..15
    const int sk0  = (tid & 31) * 24;        // k base

    // combine-phase role (threads 0..95)
    const int cj = tid % 6;                  // unit within group
    const int cb = tid / 6;                  // batch within group
    float c_reg = 0.f;                       // cell state, register-resident

    unsigned* mycnt = flags + c * 128 * FPAD;   // 8 line-padded counters used

    __builtin_amdgcn_fence(__ATOMIC_ACQUIRE, "agent");  // once: clear poison
    __syncthreads();

    for (int t = 0; t < T_LEN; ++t) {
        // ---- prefetch xg[t]: consumer-dense, 4 x 192-B coalesced runs ----
        float xpi = 0.f, xpf = 0.f, xpg = 0.f, xpo = 0.f;
        if (tid < 96) {
            const size_t xbase = (((size_t)t * 2 + c) * 128 + r) * 384 + tid;
            xpi = __half2float(xg[xbase + 0 * 96]);
            xpf = __half2float(xg[xbase + 1 * 96]);
            xpg = __half2float(xg[xbase + 2 * 96]);
            xpo = __half2float(xg[xbase + 3 * 96]);
        }

        if (t == 0) {
            for (int i = tid; i < 384; i += 512) G[i] = 0.f;  // h_prev = 0
            __syncthreads();
        } else {
            // ---- wait: 8 aggregate counters reach 16*t (wave-7 pollers) ----
            if (tid >= 448 && tid < 456) {
                const unsigned need = (unsigned)(t << 4);   // 16*t
                while (__hip_atomic_load(&mycnt[(tid - 448) * FPAD],
                                         __ATOMIC_RELAXED,
                                         __HIP_MEMORY_SCOPE_AGENT) < need) {
                    __builtin_amdgcn_s_sleep(2);   // backoff
                }
            }
            __syncthreads();

            // ---- stage packed h: 6 dwordx4 sc0 sc1 loads -> 6 uint4 LDS
            //      writes; zero unpack (words ARE the Hh/Hl rows) ----
            {
                const size_t xb = ((size_t)(c * 2 + ((t - 1) & 1)) * 16 + sb) * 768 + sk0;
                u32x4 h0, h1, h2, l0, l1, l2;
                asm volatile("global_load_dwordx4 %0, %1, off sc0 sc1"
                             : "=v"(h0) : "v"(&xch_hi[xb]));
                asm volatile("global_load_dwordx4 %0, %1, off sc0 sc1"
                             : "=v"(h1) : "v"(&xch_hi[xb + 8]));
                asm volatile("global_load_dwordx4 %0, %1, off sc0 sc1"
                             : "=v"(h2) : "v"(&xch_hi[xb + 16]));
                asm volatile("global_load_dwordx4 %0, %1, off sc0 sc1"
                             : "=v"(l0) : "v"(&xch_lo[xb]));
                asm volatile("global_load_dwordx4 %0, %1, off sc0 sc1"
                             : "=v"(l1) : "v"(&xch_lo[xb + 8]));
                asm volatile("global_load_dwordx4 %0, %1, off sc0 sc1"
                             : "=v"(l2) : "v"(&xch_lo[xb + 16]));
                asm volatile("s_waitcnt vmcnt(0)" ::: "memory");
                __builtin_amdgcn_sched_barrier(0);   // rule #18: no early use
                *(u32x4*)&Hh_s[sb * HPAD + sk0]      = h0;
                *(u32x4*)&Hh_s[sb * HPAD + sk0 + 8]  = h1;
                *(u32x4*)&Hh_s[sb * HPAD + sk0 + 16] = h2;
                *(u32x4*)&Hl_s[sb * HPAD + sk0]      = l0;
                *(u32x4*)&Hl_s[sb * HPAD + sk0 + 8]  = l1;
                *(u32x4*)&Hl_s[sb * HPAD + sk0 + 16] = l2;
            }
            __syncthreads();

            // ---- dot via MFMA: wave wv owns k in [96*wv, 96*wv+96) ----
            f32x4 acc0 = (f32x4)0.f, acc1 = (f32x4)0.f;
            const int kwb = wv * 96;
#pragma unroll
            for (int ksd = 0; ksd < 3; ++ksd) {
                const int ko = kwb + ksd * 32 + fkb;
                const short8 bh  = *(const short8*)&Hh_s[fr * HPAD + ko];
                const short8 bl  = *(const short8*)&Hl_s[fr * HPAD + ko];
                const short8 a0h = *(const short8*)&Wh_s[fr * HPAD + ko];
                const short8 a0l = *(const short8*)&Wl_s[fr * HPAD + ko];
                const short8 a1h = *(const short8*)&Wh_s[(8 + fr) * HPAD + ko];
                const short8 a1l = *(const short8*)&Wl_s[(8 + fr) * HPAD + ko];
                acc0 = __builtin_amdgcn_mfma_f32_16x16x32_bf16(a0h, bh, acc0, 0, 0, 0);
                acc0 = __builtin_amdgcn_mfma_f32_16x16x32_bf16(a0h, bl, acc0, 0, 0, 0);
                acc0 = __builtin_amdgcn_mfma_f32_16x16x32_bf16(a0l, bh, acc0, 0, 0, 0);
                acc1 = __builtin_amdgcn_mfma_f32_16x16x32_bf16(a1h, bh, acc1, 0, 0, 0);
                acc1 = __builtin_amdgcn_mfma_f32_16x16x32_bf16(a1h, bl, acc1, 0, 0, 0);
                acc1 = __builtin_amdgcn_mfma_f32_16x16x32_bf16(a1l, bh, acc1, 0, 0, 0);
            }

            // ---- stash partials (wave-major rbuf: conflict-free) ----
#pragma unroll
            for (int rix = 0; rix < 4; ++rix) {
                rbuf[wv * 512 + (rb4 + rix) * 16 + fr]        = acc0[rix];
                rbuf[wv * 512 + (16 + rb4 + rix) * 16 + fr]   = acc1[rix];
            }
            __syncthreads();

            // ---- 8-way cross-wave K-reduce -> G[24][16] ----
            if (tid < 384) {
                const int row = tid >> 4, colr = tid & 15;
                const int idx = (row < 16) ? tid : ((row + 8) * 16 + colr);
                float s = 0.f;
#pragma unroll
                for (int w = 0; w < 8; ++w) s += rbuf[w * 512 + idx];
                G[tid] = s;
            }
            __syncthreads();
        }

        // ---- gate combine: threads 0..95, one (unit, batch) each ----
        if (tid < 96) {
            const float pi = G[(0 * 6 + cj) * 16 + cb] + xpi;
            const float pf = G[(1 * 6 + cj) * 16 + cb] + xpf;
            const float pg = G[(2 * 6 + cj) * 16 + cb] + xpg;
            const float po = G[(3 * 6 + cj) * 16 + cb] + xpo;
            const float ig = 1.f / (1.f + __expf(-pi));
            const float fg = 1.f / (1.f + __expf(-pf));
            const float gg = fast_tanh(pg);
            const float og = 1.f / (1.f + __expf(-po));
            c_reg = fg * c_reg + ig * gg;
            const float h = og * fast_tanh(c_reg);
            // output: plain cached store (only read after kernel end)
            out[((size_t)(b0 + cb) * T_LEN + t) * H_SZ + u0 + cj] = h;
            // producer-side split: publish bf16 hi/lo shorts
            const unsigned ub = __float_as_uint(h);
            const unsigned uh = ub & 0xffff0000u;
            const float lo = h - __uint_as_float(uh);
            const unsigned hs = ub >> 16;
            const unsigned ls = __float_as_uint(lo) >> 16;
            const size_t pb = ((size_t)(c * 2 + (t & 1)) * 16 + cb) * 768 + u0 + cj;
            asm volatile("global_store_short %0, %1, off sc0 sc1"
                         :: "v"(&xch_hi[pb]), "v"(hs) : "memory");
            asm volatile("global_store_short %0, %1, off sc0 sc1"
                         :: "v"(&xch_lo[pb]), "v"(ls) : "memory");
        }
        // drain vmem stores, then barrier so ALL waves' stores are done
        asm volatile("s_waitcnt vmcnt(0)" ::: "memory");
        __syncthreads();

        // ---- publish: one relaxed atomic add (monotone aggregate) ----
        if (tid == 0) {
            __hip_atomic_fetch_add(&mycnt[(r & 7) * FPAD], 1u,
                                   __ATOMIC_RELAXED, __HIP_MEMORY_SCOPE_AGENT);
        }
    }
}

// ---------------------------------------------------------------------------
extern "C" void kernel_launch(void* const* d_in, const int* in_sizes, int n_in,
                              void* d_out, int out_size, void* d_ws, size_t ws_size,
                              hipStream_t stream)
{
    (void)in_sizes; (void)n_in; (void)out_size; (void)ws_size;
    const float* hidden = (const float*)d_in[0];
    const float* W_ih   = (const float*)d_in[1];
    const float* W_hh   = (const float*)d_in[2];
    const float* b_ih   = (const float*)d_in[3];
    const float* b_hh   = (const float*)d_in[4];
    float* out = (float*)d_out;

    __half* xg = (__half*)d_ws;                                  // 201,326,592 B
    unsigned* flags = (unsigned*)((char*)d_ws +
                      (size_t)T_LEN * B_SZ * G4 * sizeof(__half)); // 8192 u32

    zero_cnt<<<dim3(8), dim3(1024), 0, stream>>>(flags);
    xg_gemm<<<dim3(G4 / 128, (B_SZ * T_LEN) / 128), dim3(256), 0, stream>>>(
        hidden, W_ih, b_ih, b_hh, xg);

    const int smem = 142080;  // W 74496 + H 49664 + rbuf 16384 + G 1536
    (void)hipFuncSetAttribute((const void*)lstm_rec,
                              hipFuncAttributeMaxDynamicSharedMemorySize, smem);
    void* args[] = { (void*)&xg, (void*)&W_hh, (void*)&out, (void*)&flags };
    (void)hipLaunchCooperativeKernel((void*)lstm_rec, dim3(256), dim3(512),
                                     args, (unsigned)smem, stream);
}